// Round 5
// baseline (58.191 us; speedup 1.0000x reference)
//
#include <hip/hip_runtime.h>

// B=64, S=63, F=64, T=12, NF=63, OUT=1, C=32, K=3, DILS=(1,2,4,8,16)
//
// tcn_pre: mid layers on MFMA (f16 in, f32 accum) - unchanged from R2.
// tcn_seq (this round): barrier-free single-wave chain exploiting that only
// the k=2 tap of each layer is new per step:
//   critical path = L0 -> readlane-MAC tap2 per layer -> L4 reduce
//   taps 0/1 = off-path partial sums from old/precomputed LDS rows.

typedef _Float16 f16;
typedef _Float16 f16x4 __attribute__((ext_vector_type(4)));
typedef _Float16 f16x8 __attribute__((ext_vector_type(8)));
typedef float f32x16 __attribute__((ext_vector_type(16)));

// ---------------- workspace layout ----------------
#define OFF_H4    0                        // [64][63][12] floats
#define OFF_ST    48384                    // feature-63 state, per-b stride 1760
#define ST_L0     0                        // L0 pos 57..60   (4*32)  [pos][ch]
#define ST_L1     128                      // L1 pos 49..56   (8*32)
#define ST_L2     384                      // L2 pos 33..48   (16*32)
#define ST_L3     896                      // L3 pos 1..27    (27*32)
#define ST_STRIDE 1760
#define OFF_H40   (48384 + 64*1760)        // [64]
#define OFF_WPK   161088                   // float offset; f16 region after

#define RPAD 36
#define NROW 100

// ---------------- weight repack: fragment-ready f16 ----------------
__global__ __launch_bounds__(256) void repack_w(const float* __restrict__ wmid,
                                                f16* __restrict__ wpk) {
  const int idx = blockIdx.x * 256 + threadIdx.x;   // 589824 total
  const int j = idx & 7, r1 = idx >> 3;
  const int lane = r1 & 63, r2 = r1 >> 6;
  const int h = r2 & 1, r3 = r2 >> 1;
  const int t = r3 % 3, r4 = r3 / 3;
  const int f = r4 & 63, m = r4 >> 6;
  const int co = lane & 31;
  const int ci = h * 16 + (lane >> 5) * 8 + j;
  wpk[idx] = (f16)wmid[m * 196608 + (f * 32 + co) * 96 + ci * 3 + t];
}

// ---------------- MFMA tile for one mid layer ----------------
__device__ __forceinline__ void mfma_tile(
    int m, const f16* IN, f16* OUT, int d, int base,
    const f16* __restrict__ wpk, int f, int lane, const float* sBias)
{
  const int lg = lane >> 5;
  const int col = base + (lane & 31);

  f16x8 afr[6];
  const f16* wb = wpk + (m * 64 + f) * 6 * 512 + lane * 8;
#pragma unroll
  for (int u = 0; u < 6; ++u)
    afr[u] = *(const f16x8*)(wb + u * 512);

  f32x16 acc;
#pragma unroll
  for (int r = 0; r < 16; ++r)
    acc[r] = sBias[(r & 3) + 8 * (r >> 2) + 4 * lg];

#pragma unroll
  for (int t = 0; t < 3; ++t) {
#pragma unroll
    for (int h = 0; h < 2; ++h) {
      const f16* bp = IN + (col + t * d) * RPAD + h * 16 + lg * 8;
      f16x4 lo = *(const f16x4*)bp;
      f16x4 hi = *(const f16x4*)(bp + 4);
      f16x8 b = __builtin_shufflevector(lo, hi, 0, 1, 2, 3, 4, 5, 6, 7);
      acc = __builtin_amdgcn_mfma_f32_32x32x16_f16(afr[t * 2 + h], b, acc, 0, 0, 0);
    }
  }

#pragma unroll
  for (int q = 0; q < 4; ++q) {
    const int co0 = q * 8 + 4 * lg;
    f16x4 w;
#pragma unroll
    for (int e = 0; e < 4; ++e)
      w[e] = (f16)fmaxf(acc[q * 4 + e], 0.f);
    *(f16x4*)(OUT + col * RPAD + co0) = w;
  }
}

// ---------------- kernel A: parallel precompute ----------------
__global__ __launch_bounds__(256) void tcn_pre(
    const float* __restrict__ x, const float* __restrict__ xfc,
    const float* __restrict__ w0, const float* __restrict__ b0,
    const float* __restrict__ bmid,
    const float* __restrict__ wlast, const float* __restrict__ blast,
    const f16* __restrict__ wpk, float* __restrict__ ws)
{
  const int blk = blockIdx.x;
  const int b = blk >> 6;
  const int f = blk & 63;
  const bool lastf = (f == 63);
  const int tid = threadIdx.x;
  const int lane = tid & 63;
  const int g = __builtin_amdgcn_readfirstlane(tid >> 6);

  __shared__ float sIn[80];
  __shared__ float sBias[3][32];
  __shared__ f16 actA[NROW * RPAD];
  __shared__ f16 actB[NROW * RPAD];

  for (int t = tid; t < 80; t += 256) {
    float v = 0.f;
    if (t < 63)                 v = x[(b * 63 + t) * 64 + f];
    else if (t < 74 && !lastf)  v = xfc[(b * 12 + (t - 63)) * 63 + f];
    sIn[t] = v;
  }
  if (tid < 96) sBias[tid >> 5][tid & 31] = bmid[(tid >> 5) * 2048 + f * 32 + (tid & 31)];
  for (int i = tid; i < (NROW - 72) * RPAD; i += 256) actA[72 * RPAD + i] = (f16)0.f;
  for (int i = tid; i < (NROW - 68) * RPAD; i += 256) actB[68 * RPAD + i] = (f16)0.f;
  __syncthreads();

  // ---- L0 (d=1, 1->32ch), pos 0..71 ----
  {
    const float* wb  = w0 + (f * 32 + g * 8) * 3;
    const float* bbp = b0 + f * 32 + g * 8;
#pragma unroll
    for (int it = 0; it < 2; ++it) {
      const int p = lane + it * 64;
      if (p < 72) {
        const float i0 = sIn[p], i1 = sIn[p + 1], i2 = sIn[p + 2];
        f16x4 wv[2];
#pragma unroll
        for (int j = 0; j < 8; ++j) {
          float v = fmaf(wb[j * 3 + 0], i0,
                    fmaf(wb[j * 3 + 1], i1,
                    fmaf(wb[j * 3 + 2], i2, bbp[j])));
          wv[j >> 2][j & 3] = (f16)fmaxf(v, 0.f);
        }
        *(f16x4*)(actA + p * RPAD + g * 8)     = wv[0];
        *(f16x4*)(actA + p * RPAD + g * 8 + 4) = wv[1];
      }
    }
  }
  __syncthreads();

  float* st = ws + OFF_ST + b * ST_STRIDE;

  // ---- L1 (d=2) ----
  if (lastf) {
    for (int t = tid; t < 128; t += 256)
      st[ST_L0 + t] = (float)actA[(57 + (t >> 5)) * RPAD + (t & 31)];
  }
  if (g < 3) mfma_tile(0, actA, actB, 2, g * 32, wpk, f, lane, sBias[0]);
  __syncthreads();

  // ---- L2 (d=4) ----
  if (lastf) {
    for (int t = tid; t < 256; t += 256)
      st[ST_L1 + t] = (float)actB[(49 + (t >> 5)) * RPAD + (t & 31)];
  }
  if (g < 2) mfma_tile(1, actB, actA, 4, g * 32, wpk, f, lane, sBias[1]);
  __syncthreads();

  // ---- L3 (d=8) ----
  if (lastf) {
    for (int t = tid; t < 512; t += 256)
      st[ST_L2 + t] = (float)actA[(33 + (t >> 5)) * RPAD + (t & 31)];
  }
  if (g < 2) mfma_tile(2, actA, actB, 8, g * 32, wpk, f, lane, sBias[2]);
  __syncthreads();

  // ---- L4 (d=16, 32->1, no relu) ----
  if (lastf) {
    for (int t = tid; t < 864; t += 256)
      st[ST_L3 + t] = (float)actB[(1 + (t >> 5)) * RPAD + (t & 31)];
  }
  if (tid < 12) {
    const int p = tid;
    float acc = blast[f];
    const float* wl = wlast + f * 96;
#pragma unroll
    for (int k = 0; k < 3; ++k) {
      const int row = p + 16 * k;
#pragma unroll
      for (int ci0 = 0; ci0 < 32; ci0 += 4) {
        f16x4 av = *(const f16x4*)(actB + row * RPAD + ci0);
#pragma unroll
        for (int e = 0; e < 4; ++e)
          acc = fmaf(wl[(ci0 + e) * 3 + k], (float)av[e], acc);
      }
    }
    if (!lastf)      ws[OFF_H4 + (b * 63 + f) * 12 + p] = acc;
    else if (p == 0) ws[OFF_H40 + b] = acc;
  }
}

// ---------------- kernel B: sequential feature-63 chain ----------------

__device__ __forceinline__ float rlane(float v, int l) {
  return __uint_as_float(__builtin_amdgcn_readlane(__float_as_uint(v), l));
}

// off-path taps 0/1 partial: sum over 16 ci (this half) of 2 taps
__device__ __forceinline__ float a01_sum(const float* __restrict__ SIN,
                                         int r0, int r1,
                                         const float2* __restrict__ wp) {
  const float4* p0 = reinterpret_cast<const float4*>(SIN + r0 * 32);
  const float4* p1 = reinterpret_cast<const float4*>(SIN + r1 * 32);
  float au[16], av[16];
#pragma unroll
  for (int i = 0; i < 4; ++i) {
    const float4 u = p0[i], v = p1[i];
    au[i * 4 + 0] = u.x; au[i * 4 + 1] = u.y; au[i * 4 + 2] = u.z; au[i * 4 + 3] = u.w;
    av[i * 4 + 0] = v.x; av[i * 4 + 1] = v.y; av[i * 4 + 2] = v.z; av[i * 4 + 3] = v.w;
  }
  float q[4] = {0.f, 0.f, 0.f, 0.f};
#pragma unroll
  for (int i = 0; i < 16; ++i) {
    const float2 w = wp[i];
    q[i & 3] = fmaf(w.x, au[i], fmaf(w.y, av[i], q[i & 3]));
  }
  return (q[0] + q[1]) + (q[2] + q[3]);
}

// on-path tap2: 32-ci readlane-MAC, 4-way ILP. WTI = layer const.
#define RL32(WTI, SRC, DST) do {                                         \
    float t0_ = 0.f, t1_ = 0.f, t2_ = 0.f, t3_ = 0.f;                    \
    _Pragma("unroll")                                                    \
    for (int q_ = 0; q_ < 8; ++q_) {                                     \
      t0_ = fmaf(wt2[WTI][q_],      rlane(SRC, q_),      t0_);           \
      t1_ = fmaf(wt2[WTI][8 + q_],  rlane(SRC, 8 + q_),  t1_);           \
      t2_ = fmaf(wt2[WTI][16 + q_], rlane(SRC, 16 + q_), t2_);           \
      t3_ = fmaf(wt2[WTI][24 + q_], rlane(SRC, 24 + q_), t3_);           \
    }                                                                    \
    DST = (t0_ + t1_) + (t2_ + t3_);                                     \
  } while (0)

__global__ __launch_bounds__(64, 1) void tcn_seq(
    const float* __restrict__ x, const float* __restrict__ xfc,
    const float* __restrict__ w0, const float* __restrict__ b0,
    const float* __restrict__ wmid, const float* __restrict__ bmid,
    const float* __restrict__ wlast, const float* __restrict__ blast,
    const float* __restrict__ linW, const float* __restrict__ linb,
    const float* __restrict__ ws, float* __restrict__ out)
{
  const int b = blockIdx.x;
  const int tid = threadIdx.x;
  const int c = tid & 31;
  const int h = tid >> 5;
  const int cib = h * 16;

  __shared__ __align__(16) float L0s[15 * 32];   // pos 57..71  (idx p-57)
  __shared__ __align__(16) float L1s[19 * 32];   // pos 49..67  (idx p-49)
  __shared__ __align__(16) float L2s[27 * 32];   // pos 33..59  (idx p-33)
  __shared__ __align__(16) float L3s[27 * 32];   // pos 1..27   (idx p-1)
  __shared__ __align__(8)  float wms01[3 * 32 * 66];  // taps01 weights [m][co][ci*2+k]

  // ---- stage taps01 weights into LDS ----
  for (int t = tid; t < 6144; t += 64) {
    const int k  = t & 1;
    const int ci = (t >> 1) & 31;
    const int co = (t >> 6) & 31;
    const int m  = t >> 11;
    wms01[m * 2112 + co * 66 + ci * 2 + k] =
        wmid[m * 196608 + (2016 + co) * 96 + ci * 3 + k];
  }

  // ---- stage precomputed feature-63 state into LDS ----
  {
    const float* stp = ws + OFF_ST + b * ST_STRIDE;
    for (int t = tid; t < 128; t += 64) L0s[t] = stp[ST_L0 + t];
    for (int t = tid; t < 256; t += 64) L1s[t] = stp[ST_L1 + t];
    for (int t = tid; t < 512; t += 64) L2s[t] = stp[ST_L2 + t];
    for (int t = tid; t < 864; t += 64) L3s[t] = stp[ST_L3 + t];
  }

  // ---- linear partials accv[i] (all terms except feature 63) ----
  const float lw63 = linW[63];
  const float lb0  = linb[0];
  float accv[12];
  {
    float lw = 0.f, lwx = 0.f;
    if (tid < 63) { lw = linW[tid]; lwx = linW[64 + tid]; }
    float h4v[12], xv[12];
#pragma unroll
    for (int i = 0; i < 12; ++i) { h4v[i] = 0.f; xv[i] = 0.f; }
    if (tid < 63) {
      const float* hp = ws + OFF_H4 + (b * 63 + tid) * 12;
#pragma unroll
      for (int t = 0; t < 3; ++t) {
        const float4 v = *reinterpret_cast<const float4*>(hp + t * 4);
        h4v[t * 4 + 0] = v.x; h4v[t * 4 + 1] = v.y;
        h4v[t * 4 + 2] = v.z; h4v[t * 4 + 3] = v.w;
      }
#pragma unroll
      for (int i = 0; i < 12; ++i) xv[i] = xfc[(b * 12 + i) * 63 + tid];
    }
#pragma unroll
    for (int i = 0; i < 12; ++i) accv[i] = fmaf(lw, h4v[i], lwx * xv[i]);
#pragma unroll
    for (int r = 1; r < 64; r <<= 1) {
#pragma unroll
      for (int i = 0; i < 12; ++i) accv[i] += __shfl_xor(accv[i], r);
    }
#pragma unroll
    for (int i = 0; i < 12; ++i) accv[i] += lb0;
  }

  // ---- per-lane weights: tap2 (k=2) into registers ----
  float wt2[3][32];
#pragma unroll
  for (int m = 0; m < 3; ++m)
#pragma unroll
    for (int ci = 0; ci < 32; ++ci)
      wt2[m][ci] = wmid[m * 196608 + (2016 + c) * 96 + ci * 3 + 2];

  // ---- small per-lane params ----
  const float w00 = w0[(2016 + c) * 3 + 0];
  const float w01 = w0[(2016 + c) * 3 + 1];
  const float w02 = w0[(2016 + c) * 3 + 2];
  const float b00 = b0[2016 + c];
  const float bm0 = bmid[0 * 2048 + 2016 + c];
  const float bm1 = bmid[1 * 2048 + 2016 + c];
  const float bm2 = bmid[2 * 2048 + 2016 + c];
  const float wl0 = wlast[63 * 96 + c * 3 + 0];
  const float wl1 = wlast[63 * 96 + c * 3 + 1];
  const float wl2 = wlast[63 * 96 + c * 3 + 2];
  const float bl   = blast[63];
  const float xv61 = x[(b * 63 + 61) * 64 + 63];
  const float xv62 = x[(b * 63 + 62) * 64 + 63];
  const float h40v = ws[OFF_H40 + b];

  // taps01 weight base pointers (this lane's co row, this half's ci block)
  const float2* wp0 = reinterpret_cast<const float2*>(wms01) + c * 33 + cib;
  const float2* wp1 = reinterpret_cast<const float2*>(wms01 + 2112) + c * 33 + cib;
  const float2* wp2 = reinterpret_cast<const float2*>(wms01 + 4224) + c * 33 + cib;

  __syncthreads();   // one-time: staging visible (single wave; paranoia)

  float outv[12];
  outv[0] = fmaf(lw63, h40v, accv[0]);
  if (tid == 0) out[b * 12 + 0] = outv[0];

#pragma unroll
  for (int s = 1; s < 12; ++s) {
    // ---- L0 @ pos 60+s (in-lane, ci=c; dup across halves) ----
    const float i0 = (s == 1) ? xv61 : ((s == 2) ? xv62 : outv[s - 3]);
    const float i1 = (s == 1) ? xv62 : outv[s - 2];
    const float i2 = outv[s - 1];
    const float nL0 = fmaxf(fmaf(w00, i0, fmaf(w01, i1, fmaf(w02, i2, b00))), 0.f);
    L0s[(3 + s) * 32 + c] = nL0;

    // ---- off-path taps 0/1 partials (old / precomputed rows) ----
    float a1 = a01_sum(L0s + cib, s - 1, s + 1, wp0);   // L1 taps @56+s,58+s
    float a2 = a01_sum(L1s + cib, s - 1, s + 3, wp1);   // L2 taps @48+s,52+s
    float a3 = a01_sum(L2s + cib, s - 1, s + 7, wp2);   // L3 taps @32+s,40+s
    a1 += __shfl_xor(a1, 32);
    a2 += __shfl_xor(a2, 32);
    a3 += __shfl_xor(a3, 32);

    // ---- on-path tap2 chain via readlane-MAC ----
    float t2s;
    RL32(0, nL0, t2s);
    const float nL1 = fmaxf(t2s + a1 + bm0, 0.f);
    L1s[(7 + s) * 32 + c] = nL1;
    RL32(1, nL1, t2s);
    const float nL2 = fmaxf(t2s + a2 + bm1, 0.f);
    L2s[(15 + s) * 32 + c] = nL2;
    RL32(2, nL2, t2s);
    const float nL3 = fmaxf(t2s + a3 + bm2, 0.f);
    // (nL3 never re-read from LDS: L4's taps 0/1 are always precomputed)

    // ---- L4 @ s: per-lane products + 5-round xor reduce ----
    float p = fmaf(wl0, L3s[(s - 1) * 32 + c],
              fmaf(wl1, L3s[(15 + s) * 32 + c], wl2 * nL3));
#pragma unroll
    for (int r = 1; r < 32; r <<= 1) p += __shfl_xor(p, r);
    const float h4x = p + bl;
    outv[s] = fmaf(lw63, h4x, accv[s]);
    if (tid == 0) out[b * 12 + s] = outv[s];
  }
}

// ---------------- launcher ----------------

extern "C" void kernel_launch(void* const* d_in, const int* in_sizes, int n_in,
                              void* d_out, int out_size, void* d_ws, size_t ws_size,
                              hipStream_t stream) {
  const float* x     = (const float*)d_in[0];
  const float* xfc   = (const float*)d_in[1];
  const float* w0    = (const float*)d_in[2];
  const float* b0    = (const float*)d_in[3];
  const float* wmid  = (const float*)d_in[4];
  const float* bmid  = (const float*)d_in[5];
  const float* wlast = (const float*)d_in[6];
  const float* blast = (const float*)d_in[7];
  const float* linW  = (const float*)d_in[8];
  const float* linb  = (const float*)d_in[9];
  float* out = (float*)d_out;
  float* ws  = (float*)d_ws;
  f16* wpk = (f16*)(ws + OFF_WPK);

  repack_w<<<2304, 256, 0, stream>>>(wmid, wpk);
  tcn_pre<<<64 * 64, 256, 0, stream>>>(x, xfc, w0, b0, bmid, wlast, blast, wpk, ws);
  tcn_seq<<<64, 64, 0, stream>>>(x, xfc, w0, b0, wmid, bmid, wlast, blast, linW, linb, ws, out);
}

// Round 6
// 47.709 us; speedup vs baseline: 1.2197x; 1.2197x over previous
//
#include <hip/hip_runtime.h>

// B=64, S=63, F=64, T=12, NF=63, OUT=1, C=32, K=3, DILS=(1,2,4,8,16)
//
// tcn_pre: mid layers on MFMA (f16 in, f32 accum) - unchanged from R2.
// tcn_seq (R6): single-wave chain, NOT unrolled (I$-resident loop body),
// zero barriers, L4 taps0/1 folded into setup, tap2 via LDS roundtrip.

typedef _Float16 f16;
typedef _Float16 f16x4 __attribute__((ext_vector_type(4)));
typedef _Float16 f16x8 __attribute__((ext_vector_type(8)));
typedef float f32x16 __attribute__((ext_vector_type(16)));

// ---------------- workspace layout ----------------
#define OFF_H4    0                        // [64][63][12] floats
#define OFF_ST    48384                    // feature-63 state, per-b stride 1760
#define ST_L0     0                        // L0 pos 57..60   (4*32)  [pos][ch]
#define ST_L1     128                      // L1 pos 49..56   (8*32)
#define ST_L2     384                      // L2 pos 33..48   (16*32)
#define ST_L3     896                      // L3 pos 1..27    (27*32)
#define ST_STRIDE 1760
#define OFF_H40   (48384 + 64*1760)        // [64]
#define OFF_WPK   161088                   // float offset; f16 region after

#define RPAD 36
#define NROW 100

// ---------------- weight repack: fragment-ready f16 ----------------
__global__ __launch_bounds__(256) void repack_w(const float* __restrict__ wmid,
                                                f16* __restrict__ wpk) {
  const int idx = blockIdx.x * 256 + threadIdx.x;   // 589824 total
  const int j = idx & 7, r1 = idx >> 3;
  const int lane = r1 & 63, r2 = r1 >> 6;
  const int h = r2 & 1, r3 = r2 >> 1;
  const int t = r3 % 3, r4 = r3 / 3;
  const int f = r4 & 63, m = r4 >> 6;
  const int co = lane & 31;
  const int ci = h * 16 + (lane >> 5) * 8 + j;
  wpk[idx] = (f16)wmid[m * 196608 + (f * 32 + co) * 96 + ci * 3 + t];
}

// ---------------- MFMA tile for one mid layer ----------------
__device__ __forceinline__ void mfma_tile(
    int m, const f16* IN, f16* OUT, int d, int base,
    const f16* __restrict__ wpk, int f, int lane, const float* sBias)
{
  const int lg = lane >> 5;
  const int col = base + (lane & 31);

  f16x8 afr[6];
  const f16* wb = wpk + (m * 64 + f) * 6 * 512 + lane * 8;
#pragma unroll
  for (int u = 0; u < 6; ++u)
    afr[u] = *(const f16x8*)(wb + u * 512);

  f32x16 acc;
#pragma unroll
  for (int r = 0; r < 16; ++r)
    acc[r] = sBias[(r & 3) + 8 * (r >> 2) + 4 * lg];

#pragma unroll
  for (int t = 0; t < 3; ++t) {
#pragma unroll
    for (int h = 0; h < 2; ++h) {
      const f16* bp = IN + (col + t * d) * RPAD + h * 16 + lg * 8;
      f16x4 lo = *(const f16x4*)bp;
      f16x4 hi = *(const f16x4*)(bp + 4);
      f16x8 b = __builtin_shufflevector(lo, hi, 0, 1, 2, 3, 4, 5, 6, 7);
      acc = __builtin_amdgcn_mfma_f32_32x32x16_f16(afr[t * 2 + h], b, acc, 0, 0, 0);
    }
  }

#pragma unroll
  for (int q = 0; q < 4; ++q) {
    const int co0 = q * 8 + 4 * lg;
    f16x4 w;
#pragma unroll
    for (int e = 0; e < 4; ++e)
      w[e] = (f16)fmaxf(acc[q * 4 + e], 0.f);
    *(f16x4*)(OUT + col * RPAD + co0) = w;
  }
}

// ---------------- kernel A: parallel precompute ----------------
__global__ __launch_bounds__(256) void tcn_pre(
    const float* __restrict__ x, const float* __restrict__ xfc,
    const float* __restrict__ w0, const float* __restrict__ b0,
    const float* __restrict__ bmid,
    const float* __restrict__ wlast, const float* __restrict__ blast,
    const f16* __restrict__ wpk, float* __restrict__ ws)
{
  const int blk = blockIdx.x;
  const int b = blk >> 6;
  const int f = blk & 63;
  const bool lastf = (f == 63);
  const int tid = threadIdx.x;
  const int lane = tid & 63;
  const int g = __builtin_amdgcn_readfirstlane(tid >> 6);

  __shared__ float sIn[80];
  __shared__ float sBias[3][32];
  __shared__ f16 actA[NROW * RPAD];
  __shared__ f16 actB[NROW * RPAD];

  for (int t = tid; t < 80; t += 256) {
    float v = 0.f;
    if (t < 63)                 v = x[(b * 63 + t) * 64 + f];
    else if (t < 74 && !lastf)  v = xfc[(b * 12 + (t - 63)) * 63 + f];
    sIn[t] = v;
  }
  if (tid < 96) sBias[tid >> 5][tid & 31] = bmid[(tid >> 5) * 2048 + f * 32 + (tid & 31)];
  for (int i = tid; i < (NROW - 72) * RPAD; i += 256) actA[72 * RPAD + i] = (f16)0.f;
  for (int i = tid; i < (NROW - 68) * RPAD; i += 256) actB[68 * RPAD + i] = (f16)0.f;
  __syncthreads();

  // ---- L0 (d=1, 1->32ch), pos 0..71 ----
  {
    const float* wb  = w0 + (f * 32 + g * 8) * 3;
    const float* bbp = b0 + f * 32 + g * 8;
#pragma unroll
    for (int it = 0; it < 2; ++it) {
      const int p = lane + it * 64;
      if (p < 72) {
        const float i0 = sIn[p], i1 = sIn[p + 1], i2 = sIn[p + 2];
        f16x4 wv[2];
#pragma unroll
        for (int j = 0; j < 8; ++j) {
          float v = fmaf(wb[j * 3 + 0], i0,
                    fmaf(wb[j * 3 + 1], i1,
                    fmaf(wb[j * 3 + 2], i2, bbp[j])));
          wv[j >> 2][j & 3] = (f16)fmaxf(v, 0.f);
        }
        *(f16x4*)(actA + p * RPAD + g * 8)     = wv[0];
        *(f16x4*)(actA + p * RPAD + g * 8 + 4) = wv[1];
      }
    }
  }
  __syncthreads();

  float* st = ws + OFF_ST + b * ST_STRIDE;

  // ---- L1 (d=2) ----
  if (lastf) {
    for (int t = tid; t < 128; t += 256)
      st[ST_L0 + t] = (float)actA[(57 + (t >> 5)) * RPAD + (t & 31)];
  }
  if (g < 3) mfma_tile(0, actA, actB, 2, g * 32, wpk, f, lane, sBias[0]);
  __syncthreads();

  // ---- L2 (d=4) ----
  if (lastf) {
    for (int t = tid; t < 256; t += 256)
      st[ST_L1 + t] = (float)actB[(49 + (t >> 5)) * RPAD + (t & 31)];
  }
  if (g < 2) mfma_tile(1, actB, actA, 4, g * 32, wpk, f, lane, sBias[1]);
  __syncthreads();

  // ---- L3 (d=8) ----
  if (lastf) {
    for (int t = tid; t < 512; t += 256)
      st[ST_L2 + t] = (float)actA[(33 + (t >> 5)) * RPAD + (t & 31)];
  }
  if (g < 2) mfma_tile(2, actA, actB, 8, g * 32, wpk, f, lane, sBias[2]);
  __syncthreads();

  // ---- L4 (d=16, 32->1, no relu) ----
  if (lastf) {
    for (int t = tid; t < 864; t += 256)
      st[ST_L3 + t] = (float)actB[(1 + (t >> 5)) * RPAD + (t & 31)];
  }
  if (tid < 12) {
    const int p = tid;
    float acc = blast[f];
    const float* wl = wlast + f * 96;
#pragma unroll
    for (int k = 0; k < 3; ++k) {
      const int row = p + 16 * k;
#pragma unroll
      for (int ci0 = 0; ci0 < 32; ci0 += 4) {
        f16x4 av = *(const f16x4*)(actB + row * RPAD + ci0);
#pragma unroll
        for (int e = 0; e < 4; ++e)
          acc = fmaf(wl[(ci0 + e) * 3 + k], (float)av[e], acc);
      }
    }
    if (!lastf)      ws[OFF_H4 + (b * 63 + f) * 12 + p] = acc;
    else if (p == 0) ws[OFF_H40 + b] = acc;
  }
}

// ---------------- kernel B: sequential feature-63 chain ----------------

__device__ __forceinline__ void load16(const float* p, float* r) {
  const float4* q = reinterpret_cast<const float4*>(p);
  const float4 v0 = q[0], v1 = q[1], v2 = q[2], v3 = q[3];
  r[0]=v0.x;  r[1]=v0.y;  r[2]=v0.z;  r[3]=v0.w;
  r[4]=v1.x;  r[5]=v1.y;  r[6]=v1.z;  r[7]=v1.w;
  r[8]=v2.x;  r[9]=v2.y;  r[10]=v2.z; r[11]=v2.w;
  r[12]=v3.x; r[13]=v3.y; r[14]=v3.z; r[15]=v3.w;
}

// taps 0/1 partial: 16 ci (this half), 2 taps, weights from regs
__device__ __forceinline__ float dot01(const float* wr, const float* r0, const float* r1) {
  float q0 = 0.f, q1 = 0.f, q2 = 0.f, q3 = 0.f;
#pragma unroll
  for (int i = 0; i < 16; i += 4) {
    q0 = fmaf(wr[(i+0)*3+0], r0[i+0], fmaf(wr[(i+0)*3+1], r1[i+0], q0));
    q1 = fmaf(wr[(i+1)*3+0], r0[i+1], fmaf(wr[(i+1)*3+1], r1[i+1], q1));
    q2 = fmaf(wr[(i+2)*3+0], r0[i+2], fmaf(wr[(i+2)*3+1], r1[i+2], q2));
    q3 = fmaf(wr[(i+3)*3+0], r0[i+3], fmaf(wr[(i+3)*3+1], r1[i+3], q3));
  }
  return (q0 + q1) + (q2 + q3);
}

// tap 2 partial: 16 ci (this half) of the just-written row
__device__ __forceinline__ float dot2(const float* wr, const float* rn) {
  float q0 = 0.f, q1 = 0.f, q2 = 0.f, q3 = 0.f;
#pragma unroll
  for (int i = 0; i < 16; i += 4) {
    q0 = fmaf(wr[(i+0)*3+2], rn[i+0], q0);
    q1 = fmaf(wr[(i+1)*3+2], rn[i+1], q1);
    q2 = fmaf(wr[(i+2)*3+2], rn[i+2], q2);
    q3 = fmaf(wr[(i+3)*3+2], rn[i+3], q3);
  }
  return (q0 + q1) + (q2 + q3);
}

__global__ __launch_bounds__(64, 1) void tcn_seq(
    const float* __restrict__ x, const float* __restrict__ xfc,
    const float* __restrict__ w0, const float* __restrict__ b0,
    const float* __restrict__ wmid, const float* __restrict__ bmid,
    const float* __restrict__ wlast, const float* __restrict__ blast,
    const float* __restrict__ linW, const float* __restrict__ linb,
    const float* __restrict__ ws, float* __restrict__ out)
{
  const int b = blockIdx.x;
  const int tid = threadIdx.x;
  const int c = tid & 31;
  const int cib = (tid >> 5) * 16;

  __shared__ __align__(16) float L0s[15 * 32];   // pos 57..71  (idx p-57)
  __shared__ __align__(16) float L1s[19 * 32];   // pos 49..67  (idx p-49)
  __shared__ __align__(16) float L2s[27 * 32];   // pos 33..59  (idx p-33)
  __shared__ __align__(16) float L3s[27 * 32];   // pos 1..27   (idx p-1)
  __shared__ float preArr[12];

  // ---- stage precomputed feature-63 state into LDS ----
  {
    const float* stp = ws + OFF_ST + b * ST_STRIDE;
    for (int t = tid; t < 128; t += 64) L0s[t] = stp[ST_L0 + t];
    for (int t = tid; t < 256; t += 64) L1s[t] = stp[ST_L1 + t];
    for (int t = tid; t < 512; t += 64) L2s[t] = stp[ST_L2 + t];
    for (int t = tid; t < 864; t += 64) L3s[t] = stp[ST_L3 + t];
  }

  // ---- per-lane mid weights into registers (source-linear: wr[lci*3+k]) ----
  float wr0[48], wr1[48], wr2[48];
  {
    const float* base = wmid + (2016 + c) * 96 + cib * 3;
#pragma unroll
    for (int t = 0; t < 12; ++t) {
      const float4 v = *reinterpret_cast<const float4*>(base + t * 4);
      wr0[t*4+0] = v.x; wr0[t*4+1] = v.y; wr0[t*4+2] = v.z; wr0[t*4+3] = v.w;
    }
#pragma unroll
    for (int t = 0; t < 12; ++t) {
      const float4 v = *reinterpret_cast<const float4*>(base + 196608 + t * 4);
      wr1[t*4+0] = v.x; wr1[t*4+1] = v.y; wr1[t*4+2] = v.z; wr1[t*4+3] = v.w;
    }
#pragma unroll
    for (int t = 0; t < 12; ++t) {
      const float4 v = *reinterpret_cast<const float4*>(base + 2 * 196608 + t * 4);
      wr2[t*4+0] = v.x; wr2[t*4+1] = v.y; wr2[t*4+2] = v.z; wr2[t*4+3] = v.w;
    }
  }

  // ---- small per-lane params ----
  const float w00 = w0[(2016 + c) * 3 + 0];
  const float w01 = w0[(2016 + c) * 3 + 1];
  const float w02 = w0[(2016 + c) * 3 + 2];
  const float b00 = b0[2016 + c];
  const float bm0 = bmid[0 * 2048 + 2016 + c];
  const float bm1 = bmid[1 * 2048 + 2016 + c];
  const float bm2 = bmid[2 * 2048 + 2016 + c];
  const float wl0c = wlast[63 * 96 + c * 3 + 0];
  const float wl1c = wlast[63 * 96 + c * 3 + 1];
  const float wl2c = wlast[63 * 96 + c * 3 + 2];
  const float bl   = blast[63];
  const float lw63 = linW[63];
  const float lb0  = linb[0];
  const float xv61 = x[(b * 63 + 61) * 64 + 63];
  const float xv62 = x[(b * 63 + 62) * 64 + 63];
  const float h40v = ws[OFF_H40 + b];

  // ---- linear partials accv[i] + folded L4-taps01 (all off-chain terms) ----
  float accv[12];
  {
    float lw = 0.f, lwx = 0.f;
    if (tid < 63) { lw = linW[tid]; lwx = linW[64 + tid]; }
    float h4v[12], xv[12];
#pragma unroll
    for (int i = 0; i < 12; ++i) { h4v[i] = 0.f; xv[i] = 0.f; }
    if (tid < 63) {
      const float* hp = ws + OFF_H4 + (b * 63 + tid) * 12;
#pragma unroll
      for (int t = 0; t < 3; ++t) {
        const float4 v = *reinterpret_cast<const float4*>(hp + t * 4);
        h4v[t*4+0] = v.x; h4v[t*4+1] = v.y; h4v[t*4+2] = v.z; h4v[t*4+3] = v.w;
      }
#pragma unroll
      for (int i = 0; i < 12; ++i) xv[i] = xfc[(b * 12 + i) * 63 + tid];
    }
#pragma unroll
    for (int i = 0; i < 12; ++i) accv[i] = fmaf(lw, h4v[i], lwx * xv[i]);

    // fold L4 taps 0/1 (always precomputed L3 rows) into accv, lanes 0..31
    if (tid < 32) {
#pragma unroll
      for (int i = 1; i < 12; ++i) {
        const float qc = fmaf(wl0c, L3s[(i - 1) * 32 + tid],
                              wl1c * L3s[(i + 15) * 32 + tid]);
        accv[i] = fmaf(lw63, qc, accv[i]);
      }
    }
#pragma unroll
    for (int r = 1; r < 64; r <<= 1) {
#pragma unroll
      for (int i = 0; i < 12; ++i) accv[i] += __shfl_xor(accv[i], r);
    }
  }
  // preArr[i] = everything except the in-loop lw63*(wl2-reduce) term
  if (tid == 0) {
#pragma unroll
    for (int i = 1; i < 12; ++i) preArr[i] = accv[i] + lb0 + lw63 * bl;
  }

  // ---- step 0 ----
  const float out0 = fmaf(lw63, h40v, accv[0] + lb0);
  if (tid == 0) out[b * 12 + 0] = out0;
  float o1 = out0, o2 = xv62, o3 = xv61;

  // ---- steps 1..11 (NOT unrolled: keep loop body I$-resident) ----
#pragma unroll 1
  for (int s = 1; s < 12; ++s) {
    float R0[16], R1[16], N[16];
    const float preS = preArr[s];

    // L0 @ pos 60+s (all lanes; halves duplicate)
    const float nL0 = fmaxf(fmaf(w00, o3, fmaf(w01, o2, fmaf(w02, o1, b00))), 0.f);
    L0s[(3 + s) * 32 + c] = nL0;

    // ---- L1 @ 56+s ----
    load16(L0s + (s - 1) * 32 + cib, R0);
    load16(L0s + (s + 1) * 32 + cib, R1);
    const float a1 = dot01(wr0, R0, R1);
    load16(L0s + (3 + s) * 32 + cib, N);
    float v = dot2(wr0, N) + a1;
    v += __shfl_xor(v, 32);
    const float nL1 = fmaxf(v + bm0, 0.f);
    L1s[(7 + s) * 32 + c] = nL1;

    // ---- L2 @ 48+s ----
    load16(L1s + (s - 1) * 32 + cib, R0);
    load16(L1s + (s + 3) * 32 + cib, R1);
    const float a2 = dot01(wr1, R0, R1);
    load16(L1s + (7 + s) * 32 + cib, N);
    v = dot2(wr1, N) + a2;
    v += __shfl_xor(v, 32);
    const float nL2 = fmaxf(v + bm1, 0.f);
    L2s[(15 + s) * 32 + c] = nL2;

    // ---- L3 @ 32+s ----
    load16(L2s + (s - 1) * 32 + cib, R0);
    load16(L2s + (s + 7) * 32 + cib, R1);
    const float a3 = dot01(wr2, R0, R1);
    load16(L2s + (15 + s) * 32 + cib, N);
    v = dot2(wr2, N) + a3;
    v += __shfl_xor(v, 32);
    const float nL3 = fmaxf(v + bm2, 0.f);

    // ---- L4 @ s: only tap2 remains (taps 0/1 folded into preArr) ----
    float pl = wl2c * nL3;
#pragma unroll
    for (int r = 1; r < 32; r <<= 1) pl += __shfl_xor(pl, r);
    const float outs = fmaf(lw63, pl, preS);
    if (tid == 0) out[b * 12 + s] = outs;
    o3 = o2; o2 = o1; o1 = outs;
  }
}

// ---------------- launcher ----------------

extern "C" void kernel_launch(void* const* d_in, const int* in_sizes, int n_in,
                              void* d_out, int out_size, void* d_ws, size_t ws_size,
                              hipStream_t stream) {
  const float* x     = (const float*)d_in[0];
  const float* xfc   = (const float*)d_in[1];
  const float* w0    = (const float*)d_in[2];
  const float* b0    = (const float*)d_in[3];
  const float* wmid  = (const float*)d_in[4];
  const float* bmid  = (const float*)d_in[5];
  const float* wlast = (const float*)d_in[6];
  const float* blast = (const float*)d_in[7];
  const float* linW  = (const float*)d_in[8];
  const float* linb  = (const float*)d_in[9];
  float* out = (float*)d_out;
  float* ws  = (float*)d_ws;
  f16* wpk = (f16*)(ws + OFF_WPK);

  repack_w<<<2304, 256, 0, stream>>>(wmid, wpk);
  tcn_pre<<<64 * 64, 256, 0, stream>>>(x, xfc, w0, b0, bmid, wlast, blast, wpk, ws);
  tcn_seq<<<64, 64, 0, stream>>>(x, xfc, w0, b0, wmid, bmid, wlast, blast, linW, linb, ws, out);
}

// Round 7
// 46.858 us; speedup vs baseline: 1.2419x; 1.0182x over previous
//
#include <hip/hip_runtime.h>

// B=64, S=63, F=64, T=12, NF=63, OUT=1, C=32, K=3, DILS=(1,2,4,8,16)
//
// tcn_pre: mid layers on MFMA (f16 in, f32 accum).
// tcn_seq: single-wave chain, rolled loop, zero barriers, L4 taps01 folded.
// R7: ALL tcn_seq setup loads coalesced via repack-built lane-major tables:
//   rec[40][64][4] f32  (mid weights 144 + params 13 per lane)
//   xfcT[b][3][64][4]   (forecast features, lane = feature)
//   h4 relaid to [b][3][64][4] (lane = feature), f=63 slots zeroed by pre.

typedef _Float16 f16;
typedef _Float16 f16x4 __attribute__((ext_vector_type(4)));
typedef _Float16 f16x8 __attribute__((ext_vector_type(8)));
typedef float f32x16 __attribute__((ext_vector_type(16)));

// ---------------- workspace layout (float offsets) ----------------
#define OFF_H4    0                        // [64][3][64][4] = 49152
#define OFF_ST    49152                    // feature-63 state, per-b stride 1760
#define ST_L0     0                        // L0 pos 57..60   (4*32)  [pos][ch]
#define ST_L1     128                      // L1 pos 49..56   (8*32)
#define ST_L2     384                      // L2 pos 33..48   (16*32)
#define ST_L3     896                      // L3 pos 1..27    (27*32)
#define ST_STRIDE 1760                     // ends 161792
#define OFF_H40   161792                   // [64]
#define OFF_WPK   161856                   // f16 region: 589824 f16 = 294912 fl
#define OFF_REC   456768                   // rec[40][64][4] = 10240
#define OFF_XFT   467008                   // xfcT[64][3][64][4] = 49152

#define WPK_N 589824
#define REC_END 600064                     // WPK_N + 10240
#define TOT_N 649216                       // REC_END + 49152

#define RPAD 36
#define NROW 100

// ---------------- repack: MFMA weight fragments + seq setup tables ----------
__global__ __launch_bounds__(256) void repack_w(
    const float* __restrict__ wmid, const float* __restrict__ w0,
    const float* __restrict__ b0, const float* __restrict__ bmid,
    const float* __restrict__ wlast, const float* __restrict__ blast,
    const float* __restrict__ linW, const float* __restrict__ linb,
    const float* __restrict__ xfc, f16* __restrict__ wpk,
    float* __restrict__ ws)
{
  const int idx = blockIdx.x * 256 + threadIdx.x;
  if (idx < WPK_N) {
    // MFMA fragment-ready f16 weights
    const int j = idx & 7, r1 = idx >> 3;
    const int lane = r1 & 63, r2 = r1 >> 6;
    const int h = r2 & 1, r3 = r2 >> 1;
    const int t = r3 % 3, r4 = r3 / 3;
    const int f = r4 & 63, m = r4 >> 6;
    const int co = lane & 31;
    const int ci = h * 16 + (lane >> 5) * 8 + j;
    wpk[idx] = (f16)wmid[m * 196608 + (f * 32 + co) * 96 + ci * 3 + t];
  } else if (idx < REC_END) {
    // tcn_seq per-lane record, lane-major: rec[(q*64+lane)*4+e] = record[q*4+e]
    const int r = idx - WPK_N;
    const int e = r & 3, lane = (r >> 2) & 63, q = r >> 8;
    const int i = q * 4 + e;                    // 0..159 within record
    const int c = lane & 31, cib = (lane >> 5) * 16;
    float v = 0.f;
    if (i < 144) {
      const int m = i / 48, j = i % 48;
      v = wmid[m * 196608 + (2016 + c) * 96 + cib * 3 + j];
    } else {
      const int j = i - 144;
      if (j < 3)        v = w0[(2016 + c) * 3 + j];
      else if (j == 3)  v = b0[2016 + c];
      else if (j < 7)   v = bmid[(j - 4) * 2048 + 2016 + c];
      else if (j < 10)  v = wlast[63 * 96 + c * 3 + (j - 7)];
      else if (j == 10) v = blast[63];
      else if (j == 11) v = linW[63];
      else if (j == 12) v = linb[0];
    }
    ws[OFF_REC + r] = v;
  } else if (idx < TOT_N) {
    // xfcT[b][q][lane][e]: lane = feature, i = q*4+e
    const int r = idx - REC_END;
    const int b = r / 768, rem = r % 768;
    const int q = rem >> 8, lane = (rem >> 2) & 63, e = rem & 3;
    const int i = q * 4 + e;
    ws[OFF_XFT + r] = (lane < 63 && i < 12) ? xfc[(b * 12 + i) * 63 + lane] : 0.f;
  }
}

// ---------------- MFMA tile for one mid layer ----------------
__device__ __forceinline__ void mfma_tile(
    int m, const f16* IN, f16* OUT, int d, int base,
    const f16* __restrict__ wpk, int f, int lane, const float* sBias)
{
  const int lg = lane >> 5;
  const int col = base + (lane & 31);

  f16x8 afr[6];
  const f16* wb = wpk + (m * 64 + f) * 6 * 512 + lane * 8;
#pragma unroll
  for (int u = 0; u < 6; ++u)
    afr[u] = *(const f16x8*)(wb + u * 512);

  f32x16 acc;
#pragma unroll
  for (int r = 0; r < 16; ++r)
    acc[r] = sBias[(r & 3) + 8 * (r >> 2) + 4 * lg];

#pragma unroll
  for (int t = 0; t < 3; ++t) {
#pragma unroll
    for (int h = 0; h < 2; ++h) {
      const f16* bp = IN + (col + t * d) * RPAD + h * 16 + lg * 8;
      f16x4 lo = *(const f16x4*)bp;
      f16x4 hi = *(const f16x4*)(bp + 4);
      f16x8 b = __builtin_shufflevector(lo, hi, 0, 1, 2, 3, 4, 5, 6, 7);
      acc = __builtin_amdgcn_mfma_f32_32x32x16_f16(afr[t * 2 + h], b, acc, 0, 0, 0);
    }
  }

#pragma unroll
  for (int q = 0; q < 4; ++q) {
    const int co0 = q * 8 + 4 * lg;
    f16x4 w;
#pragma unroll
    for (int e = 0; e < 4; ++e)
      w[e] = (f16)fmaxf(acc[q * 4 + e], 0.f);
    *(f16x4*)(OUT + col * RPAD + co0) = w;
  }
}

// ---------------- kernel A: parallel precompute ----------------
__global__ __launch_bounds__(256) void tcn_pre(
    const float* __restrict__ x, const float* __restrict__ xfc,
    const float* __restrict__ w0, const float* __restrict__ b0,
    const float* __restrict__ bmid,
    const float* __restrict__ wlast, const float* __restrict__ blast,
    const f16* __restrict__ wpk, float* __restrict__ ws)
{
  const int blk = blockIdx.x;
  const int b = blk >> 6;
  const int f = blk & 63;
  const bool lastf = (f == 63);
  const int tid = threadIdx.x;
  const int lane = tid & 63;
  const int g = __builtin_amdgcn_readfirstlane(tid >> 6);

  __shared__ float sIn[80];
  __shared__ float sBias[3][32];
  __shared__ f16 actA[NROW * RPAD];
  __shared__ f16 actB[NROW * RPAD];

  for (int t = tid; t < 80; t += 256) {
    float v = 0.f;
    if (t < 63)                 v = x[(b * 63 + t) * 64 + f];
    else if (t < 74 && !lastf)  v = xfc[(b * 12 + (t - 63)) * 63 + f];
    sIn[t] = v;
  }
  if (tid < 96) sBias[tid >> 5][tid & 31] = bmid[(tid >> 5) * 2048 + f * 32 + (tid & 31)];
  for (int i = tid; i < (NROW - 72) * RPAD; i += 256) actA[72 * RPAD + i] = (f16)0.f;
  for (int i = tid; i < (NROW - 68) * RPAD; i += 256) actB[68 * RPAD + i] = (f16)0.f;
  __syncthreads();

  // ---- L0 (d=1, 1->32ch), pos 0..71 ----
  {
    const float* wb  = w0 + (f * 32 + g * 8) * 3;
    const float* bbp = b0 + f * 32 + g * 8;
#pragma unroll
    for (int it = 0; it < 2; ++it) {
      const int p = lane + it * 64;
      if (p < 72) {
        const float i0 = sIn[p], i1 = sIn[p + 1], i2 = sIn[p + 2];
        f16x4 wv[2];
#pragma unroll
        for (int j = 0; j < 8; ++j) {
          float v = fmaf(wb[j * 3 + 0], i0,
                    fmaf(wb[j * 3 + 1], i1,
                    fmaf(wb[j * 3 + 2], i2, bbp[j])));
          wv[j >> 2][j & 3] = (f16)fmaxf(v, 0.f);
        }
        *(f16x4*)(actA + p * RPAD + g * 8)     = wv[0];
        *(f16x4*)(actA + p * RPAD + g * 8 + 4) = wv[1];
      }
    }
  }
  __syncthreads();

  float* st = ws + OFF_ST + b * ST_STRIDE;

  // ---- L1 (d=2) ----
  if (lastf) {
    for (int t = tid; t < 128; t += 256)
      st[ST_L0 + t] = (float)actA[(57 + (t >> 5)) * RPAD + (t & 31)];
  }
  if (g < 3) mfma_tile(0, actA, actB, 2, g * 32, wpk, f, lane, sBias[0]);
  __syncthreads();

  // ---- L2 (d=4) ----
  if (lastf) {
    for (int t = tid; t < 256; t += 256)
      st[ST_L1 + t] = (float)actB[(49 + (t >> 5)) * RPAD + (t & 31)];
  }
  if (g < 2) mfma_tile(1, actB, actA, 4, g * 32, wpk, f, lane, sBias[1]);
  __syncthreads();

  // ---- L3 (d=8) ----
  if (lastf) {
    for (int t = tid; t < 512; t += 256)
      st[ST_L2 + t] = (float)actA[(33 + (t >> 5)) * RPAD + (t & 31)];
  }
  if (g < 2) mfma_tile(2, actA, actB, 8, g * 32, wpk, f, lane, sBias[2]);
  __syncthreads();

  // ---- L4 (d=16, 32->1, no relu) ----
  if (lastf) {
    for (int t = tid; t < 864; t += 256)
      st[ST_L3 + t] = (float)actB[(1 + (t >> 5)) * RPAD + (t & 31)];
  }
  if (tid < 12) {
    const int p = tid;
    float acc = blast[f];
    const float* wl = wlast + f * 96;
#pragma unroll
    for (int k = 0; k < 3; ++k) {
      const int row = p + 16 * k;
#pragma unroll
      for (int ci0 = 0; ci0 < 32; ci0 += 4) {
        f16x4 av = *(const f16x4*)(actB + row * RPAD + ci0);
#pragma unroll
        for (int e = 0; e < 4; ++e)
          acc = fmaf(wl[(ci0 + e) * 3 + k], (float)av[e], acc);
      }
    }
    // h4T[b][p>>2][f][p&3]
    if (!lastf) {
      ws[OFF_H4 + b * 768 + (p >> 2) * 256 + f * 4 + (p & 3)] = acc;
    } else {
      ws[OFF_H4 + b * 768 + (p >> 2) * 256 + 63 * 4 + (p & 3)] = 0.f;  // keep lane-63 slot finite-zero
      if (p == 0) ws[OFF_H40 + b] = acc;
    }
  }
}

// ---------------- kernel B: sequential feature-63 chain ----------------

__device__ __forceinline__ void load16(const float* p, float* r) {
  const float4* q = reinterpret_cast<const float4*>(p);
  const float4 v0 = q[0], v1 = q[1], v2 = q[2], v3 = q[3];
  r[0]=v0.x;  r[1]=v0.y;  r[2]=v0.z;  r[3]=v0.w;
  r[4]=v1.x;  r[5]=v1.y;  r[6]=v1.z;  r[7]=v1.w;
  r[8]=v2.x;  r[9]=v2.y;  r[10]=v2.z; r[11]=v2.w;
  r[12]=v3.x; r[13]=v3.y; r[14]=v3.z; r[15]=v3.w;
}

__device__ __forceinline__ float dot01(const float* wr, const float* r0, const float* r1) {
  float q0 = 0.f, q1 = 0.f, q2 = 0.f, q3 = 0.f;
#pragma unroll
  for (int i = 0; i < 16; i += 4) {
    q0 = fmaf(wr[(i+0)*3+0], r0[i+0], fmaf(wr[(i+0)*3+1], r1[i+0], q0));
    q1 = fmaf(wr[(i+1)*3+0], r0[i+1], fmaf(wr[(i+1)*3+1], r1[i+1], q1));
    q2 = fmaf(wr[(i+2)*3+0], r0[i+2], fmaf(wr[(i+2)*3+1], r1[i+2], q2));
    q3 = fmaf(wr[(i+3)*3+0], r0[i+3], fmaf(wr[(i+3)*3+1], r1[i+3], q3));
  }
  return (q0 + q1) + (q2 + q3);
}

__device__ __forceinline__ float dot2(const float* wr, const float* rn) {
  float q0 = 0.f, q1 = 0.f, q2 = 0.f, q3 = 0.f;
#pragma unroll
  for (int i = 0; i < 16; i += 4) {
    q0 = fmaf(wr[(i+0)*3+2], rn[i+0], q0);
    q1 = fmaf(wr[(i+1)*3+2], rn[i+1], q1);
    q2 = fmaf(wr[(i+2)*3+2], rn[i+2], q2);
    q3 = fmaf(wr[(i+3)*3+2], rn[i+3], q3);
  }
  return (q0 + q1) + (q2 + q3);
}

__global__ __launch_bounds__(64, 1) void tcn_seq(
    const float* __restrict__ x,
    const float* __restrict__ linW,
    const float* __restrict__ ws, float* __restrict__ out)
{
  const int b = blockIdx.x;
  const int tid = threadIdx.x;
  const int c = tid & 31;
  const int cib = (tid >> 5) * 16;

  __shared__ __align__(16) float L0s[15 * 32];   // pos 57..71  (idx p-57)
  __shared__ __align__(16) float L1s[19 * 32];   // pos 49..67  (idx p-49)
  __shared__ __align__(16) float L2s[27 * 32];   // pos 33..59  (idx p-33)
  __shared__ __align__(16) float L3s[27 * 32];   // pos 1..27   (idx p-1)
  __shared__ float preArr[12];

  // ---- stage precomputed feature-63 state into LDS (coalesced) ----
  {
    const float* stp = ws + OFF_ST + b * ST_STRIDE;
    for (int t = tid; t < 128; t += 64) L0s[t] = stp[ST_L0 + t];
    for (int t = tid; t < 256; t += 64) L1s[t] = stp[ST_L1 + t];
    for (int t = tid; t < 512; t += 64) L2s[t] = stp[ST_L2 + t];
    for (int t = tid; t < 864; t += 64) L3s[t] = stp[ST_L3 + t];
  }

  // ---- fully-coalesced setup table: 40 x b128 ----
  float wr0[48], wr1[48], wr2[48], prm[16];
  {
    const float* tab = ws + OFF_REC;
#pragma unroll
    for (int q = 0; q < 40; ++q) {
      const float4 v = *reinterpret_cast<const float4*>(tab + (q * 64 + tid) * 4);
      float* dst = (q < 12) ? &wr0[q * 4]
                 : (q < 24) ? &wr1[(q - 12) * 4]
                 : (q < 36) ? &wr2[(q - 24) * 4]
                            : &prm[(q - 36) * 4];
      dst[0] = v.x; dst[1] = v.y; dst[2] = v.z; dst[3] = v.w;
    }
  }
  const float w00 = prm[0],  w01 = prm[1],  w02 = prm[2],  b00 = prm[3];
  const float bm0 = prm[4],  bm1 = prm[5],  bm2 = prm[6];
  const float wl0c = prm[7], wl1c = prm[8], wl2c = prm[9];
  const float bl = prm[10],  lw63 = prm[11], lb0 = prm[12];

  const float xv61 = x[(b * 63 + 61) * 64 + 63];
  const float xv62 = x[(b * 63 + 62) * 64 + 63];
  const float h40v = ws[OFF_H40 + b];

  // ---- linear partials accv[i] + folded L4-taps01 (all off-chain terms) ----
  float accv[12];
  {
    float lw = 0.f, lwx = 0.f;
    if (tid < 63) { lw = linW[tid]; lwx = linW[64 + tid]; }
    float h4v[12], xv[12];
#pragma unroll
    for (int q = 0; q < 3; ++q) {  // coalesced h4T + xfcT
      const float4 hv = *reinterpret_cast<const float4*>(ws + OFF_H4 + b * 768 + q * 256 + tid * 4);
      const float4 xvv = *reinterpret_cast<const float4*>(ws + OFF_XFT + b * 768 + q * 256 + tid * 4);
      h4v[q*4+0] = hv.x; h4v[q*4+1] = hv.y; h4v[q*4+2] = hv.z; h4v[q*4+3] = hv.w;
      xv[q*4+0] = xvv.x; xv[q*4+1] = xvv.y; xv[q*4+2] = xvv.z; xv[q*4+3] = xvv.w;
    }
#pragma unroll
    for (int i = 0; i < 12; ++i) accv[i] = fmaf(lw, h4v[i], lwx * xv[i]);

    // fold L4 taps 0/1 (always precomputed L3 rows) into accv, lanes 0..31
    if (tid < 32) {
#pragma unroll
      for (int i = 1; i < 12; ++i) {
        const float qc = fmaf(wl0c, L3s[(i - 1) * 32 + tid],
                              wl1c * L3s[(i + 15) * 32 + tid]);
        accv[i] = fmaf(lw63, qc, accv[i]);
      }
    }
#pragma unroll
    for (int r = 1; r < 64; r <<= 1) {
#pragma unroll
      for (int i = 0; i < 12; ++i) accv[i] += __shfl_xor(accv[i], r);
    }
  }
  if (tid == 0) {
#pragma unroll
    for (int i = 1; i < 12; ++i) preArr[i] = accv[i] + lb0 + lw63 * bl;
  }

  // ---- step 0 ----
  const float out0 = fmaf(lw63, h40v, accv[0] + lb0);
  if (tid == 0) out[b * 12 + 0] = out0;
  float o1 = out0, o2 = xv62, o3 = xv61;

  // ---- steps 1..11 (NOT unrolled: keep loop body I$-resident) ----
#pragma unroll 1
  for (int s = 1; s < 12; ++s) {
    float R0[16], R1[16], N[16];
    const float preS = preArr[s];

    const float nL0 = fmaxf(fmaf(w00, o3, fmaf(w01, o2, fmaf(w02, o1, b00))), 0.f);
    L0s[(3 + s) * 32 + c] = nL0;

    // ---- L1 @ 56+s ----
    load16(L0s + (s - 1) * 32 + cib, R0);
    load16(L0s + (s + 1) * 32 + cib, R1);
    const float a1 = dot01(wr0, R0, R1);
    load16(L0s + (3 + s) * 32 + cib, N);
    float v = dot2(wr0, N) + a1;
    v += __shfl_xor(v, 32);
    const float nL1 = fmaxf(v + bm0, 0.f);
    L1s[(7 + s) * 32 + c] = nL1;

    // ---- L2 @ 48+s ----
    load16(L1s + (s - 1) * 32 + cib, R0);
    load16(L1s + (s + 3) * 32 + cib, R1);
    const float a2 = dot01(wr1, R0, R1);
    load16(L1s + (7 + s) * 32 + cib, N);
    v = dot2(wr1, N) + a2;
    v += __shfl_xor(v, 32);
    const float nL2 = fmaxf(v + bm1, 0.f);
    L2s[(15 + s) * 32 + c] = nL2;

    // ---- L3 @ 32+s ----
    load16(L2s + (s - 1) * 32 + cib, R0);
    load16(L2s + (s + 7) * 32 + cib, R1);
    const float a3 = dot01(wr2, R0, R1);
    load16(L2s + (15 + s) * 32 + cib, N);
    v = dot2(wr2, N) + a3;
    v += __shfl_xor(v, 32);
    const float nL3 = fmaxf(v + bm2, 0.f);

    // ---- L4 @ s: only tap2 remains (taps 0/1 folded into preArr) ----
    float pl = wl2c * nL3;
#pragma unroll
    for (int r = 1; r < 32; r <<= 1) pl += __shfl_xor(pl, r);
    const float outs = fmaf(lw63, pl, preS);
    if (tid == 0) out[b * 12 + s] = outs;
    o3 = o2; o2 = o1; o1 = outs;
  }
}

// ---------------- launcher ----------------

extern "C" void kernel_launch(void* const* d_in, const int* in_sizes, int n_in,
                              void* d_out, int out_size, void* d_ws, size_t ws_size,
                              hipStream_t stream) {
  const float* x     = (const float*)d_in[0];
  const float* xfc   = (const float*)d_in[1];
  const float* w0    = (const float*)d_in[2];
  const float* b0    = (const float*)d_in[3];
  const float* wmid  = (const float*)d_in[4];
  const float* bmid  = (const float*)d_in[5];
  const float* wlast = (const float*)d_in[6];
  const float* blast = (const float*)d_in[7];
  const float* linW  = (const float*)d_in[8];
  const float* linb  = (const float*)d_in[9];
  float* out = (float*)d_out;
  float* ws  = (float*)d_ws;
  f16* wpk = (f16*)(ws + OFF_WPK);

  repack_w<<<(TOT_N + 255) / 256, 256, 0, stream>>>(
      wmid, w0, b0, bmid, wlast, blast, linW, linb, xfc, wpk, ws);
  tcn_pre<<<64 * 64, 256, 0, stream>>>(x, xfc, w0, b0, bmid, wlast, blast, wpk, ws);
  tcn_seq<<<64, 64, 0, stream>>>(x, linW, ws, out);
}